// Round 19
// baseline (91.306 us; speedup 1.0000x reference)
//
#include <hip/hip_runtime.h>

// RNN-T (transducer) loss, B=8 T=256 U=96 H=512, f32.
// Linear-domain wavefront DP: A[t,u] = A[t-1,u]*Wb[t-1,u] + A[t,u-1]*We[t,u-1]
// Wb=exp(blank_lp), We=exp(emit_lp) precomputed by k_lse into diagonal layout:
// Wb(t,u) -> row t+u, col u, slot0;  We(t,u) -> row t+u, col u+1, slot1.
// hipMemsetAsync zeroes the ENTIRE D buffer (zero weight self-masks all
// dead/unwritten cells). k_alpha: DPP cross-lane + triple-buffered prefetch.
// NOTE (measurement round): k_lse is launched TWICE (idempotent) so
// dur = C + 2*k_lse + k_alpha -> k_lse = dur - 65.1 from R18's baseline.
constexpr int B = 8, T = 256, U = 96, H = 512;
constexpr int RW = 96, ROWS = 368;   // float2 {wb,we} per cell
constexpr int CH = 12;               // rows per k_lse chunk (straggler bound)

typedef float vf4 __attribute__((ext_vector_type(4)));

__device__ __forceinline__ float exp2i(int e) {      // e in [-126,127]
    return __uint_as_float((unsigned)(127 + e) << 23);
}

// lane l <- x[lane l-1]; lane 0 <- 0.  Pure-VALU shfl_up(x,1): DPP wave_shr:1.
__device__ __forceinline__ float dpp_up1(float x) {
    return __int_as_float(__builtin_amdgcn_update_dpp(
        0, __float_as_int(x), 0x138, 0xf, 0xf, true));
}
// fmax with row_shr:N shifted self (accumulates max toward higher lanes).
template <int CTRL>
__device__ __forceinline__ float dpp_maxshr(float x) {
    return fmaxf(x, __int_as_float(__builtin_amdgcn_update_dpp(
        0, __float_as_int(x), CTRL, 0xf, 0xf, true)));
}

// Kernel 1: one wave per 12-row chunk; 4 rows per iteration via 16-lane
// quarters (4-level reduce). PLAIN loads (no nontemporal) and
// __launch_bounds__(256,8) to pin VGPR<=64 -> full 8 waves/SIMD occupancy.
__global__ __launch_bounds__(256, 8) void k_lse(
    const float* __restrict__ x, const int* __restrict__ label,
    const int* __restrict__ f_len, const int* __restrict__ y_len,
    const int* __restrict__ blank_p, const float* __restrict__ lam_p,
    float* __restrict__ D)
{
    const int tid  = threadIdx.x;
    const int lane = tid & 63;
    const int l16  = lane & 15;
    const int q    = lane >> 4;               // quarter id = row offset
    const int chunk = (blockIdx.x << 2) | (tid >> 6);   // 0..16383
    const int b  = chunk & 7;                 // b fastest: balanced dead work
    const int t  = (chunk >> 3) & 255;
    const int u0 = (chunk >> 11) * CH;        // 0,12,...,84

    const int fb = f_len[b], yb = y_len[b];
    if (t >= fb || u0 > yb) return;                    // dead chunk
    const int nbl = min(CH, yb + 1 - u0);              // rows with Wb write
    const int nem = min(CH, yb - u0);                  // rows with We write

    const int ib   = blank_p[0];
    const float lam = lam_p[0];
    const float pen = lam * ((fb - 1.0f) * 0.5f) - lam * (float)t;

    int lbl_l = 0;                                     // labels u0..u0+11
    if (lane < CH && (u0 + lane) < U - 1)
        lbl_l = label[b * (U - 1) + u0 + lane];

    const float* xrow = x + ((size_t)(b * T + t) * U + u0) * H;
    size_t cc0 = ((size_t)b * ROWS + (t + u0)) * RW + u0;

    for (int i = 0; i < nbl; i += 4) {
        const int row = i + q;                 // quarter q handles row i+q
        const bool rv = row < nbl;
        const float* xr = xrow + (size_t)row * H;

        // scalar pre-load for the two storer lanes (latency hidden below)
        int  lbl = __shfl(lbl_l, row & 15);
        int  idx = (l16 == 0) ? ib : lbl;
        float xs = 0.f;
        if (rv && l16 < 2) xs = xr[idx];

        vf4 v[8];
        #pragma unroll
        for (int j = 0; j < 8; ++j) {
            vf4 z = {0.f, 0.f, 0.f, 0.f};
            v[j] = rv ? ((const vf4*)xr)[l16 + 16 * j] : z;
        }
        float s0 = 0.f, s1 = 0.f, s2 = 0.f, s3 = 0.f;
        #pragma unroll
        for (int j = 0; j < 8; ++j) {
            s0 += __expf(v[j].x); s1 += __expf(v[j].y);
            s2 += __expf(v[j].z); s3 += __expf(v[j].w);
        }
        float s = (s0 + s1) + (s2 + s3);
        #pragma unroll
        for (int d = 1; d < 16; d <<= 1) s += __shfl_xor(s, d);
        float rcp = __builtin_amdgcn_rcpf(s);          // W = exp(x)/s

        size_t cc = cc0 + (size_t)row * (RW + 1);
        if (rv && l16 == 0) D[cc * 2] = __expf(xs) * rcp;            // Wb
        if (rv && row < nem && l16 == 1)
            D[(cc + 1) * 2 + 1] = __expf(xs + pen) * rcp;            // We
    }
}

// Kernel 2 (R18-proven): wavefront DP. One wave per batch. Lane l (0..11)
// owns u-strip [8l, 8l+7]. Per step: 16 FMA + ONE DPP wave_shr:1. Triple-
// buffered group prefetch (2 groups ahead). Stale-by-one-group rescale.
__global__ __launch_bounds__(64) void k_alpha(
    const float* __restrict__ D_all,
    const int* __restrict__ f_len, const int* __restrict__ y_len,
    float* __restrict__ out)
{
    const int b = blockIdx.x;
    const int l = threadIdx.x;
    const float* D = D_all + (size_t)b * ROWS * RW * 2;
    const vf4* Dv = (const vf4*)D;                    // 48 vf4 per diag row
    const int lc = (l < 12) ? l : 11;
    const int fcap = f_len[b] - 1;
    const int ycap = y_len[b];
    const int kstar = fcap + ycap;                    // in [135, 350]
    const int gstar = (kstar - 1) >> 3;               // group holding kstar (>=16)

    float A[8];
    #pragma unroll
    for (int c = 0; c < 8; ++c) A[c] = 0.f;
    if (l == 0) A[0] = 1.f;                           // alpha[0,0] = 1
    float a7s = 0.f;                                  // col 8l-1 prev-diag value
    int ls_e = 0, E_prev = 0, fls = 0;
    float fin = 0.f;

    vf4 W0[8][4], W1[8][4], W2[8][4];
    #pragma unroll
    for (int r = 0; r < 8; ++r)
        #pragma unroll
        for (int qq = 0; qq < 4; ++qq) {
            W0[r][qq] = Dv[(size_t)r * (RW / 2) + lc * 4 + qq];        // grp 0
            W1[r][qq] = Dv[(size_t)(8 + r) * (RW / 2) + lc * 4 + qq];  // grp 1
        }

    #define STEP(WROW)                                                    \
    {                                                                     \
        float n7 = fmaf(A[6], (WROW)[3].w, A[7] * (WROW)[3].z);           \
        float n0 = fmaf(a7s,  (WROW)[0].y, A[0] * (WROW)[0].x);           \
        float n1 = fmaf(A[0], (WROW)[0].w, A[1] * (WROW)[0].z);           \
        float n2 = fmaf(A[1], (WROW)[1].y, A[2] * (WROW)[1].x);           \
        float n3 = fmaf(A[2], (WROW)[1].w, A[3] * (WROW)[1].z);           \
        float n4 = fmaf(A[3], (WROW)[2].y, A[4] * (WROW)[2].x);           \
        float n5 = fmaf(A[4], (WROW)[2].w, A[5] * (WROW)[2].z);           \
        float n6 = fmaf(A[5], (WROW)[3].y, A[6] * (WROW)[3].x);           \
        a7s = dpp_up1(n7);                                                \
        A[0]=n0; A[1]=n1; A[2]=n2; A[3]=n3;                               \
        A[4]=n4; A[5]=n5; A[6]=n6; A[7]=n7;                               \
    }

    // Step group gg from CUR; load group gg+2 into NXT; stale rescale.
    #define LEAN(CUR, NXT, gg)                                            \
    {                                                                     \
        _Pragma("unroll") for (int r = 0; r < 8; ++r)                     \
            _Pragma("unroll") for (int qq = 0; qq < 4; ++qq)              \
                NXT[r][qq] = Dv[((size_t)((gg)+2)*8 + r)*(RW/2) + lc*4 + qq]; \
        _Pragma("unroll") for (int r = 0; r < 8; ++r) STEP(CUR[r]);       \
        int sh = 100 - E_prev;                                            \
        float r1 = exp2i(sh >> 1), r2 = exp2i(sh - (sh >> 1));            \
        _Pragma("unroll") for (int c = 0; c < 8; ++c) A[c] = A[c]*r1*r2;  \
        a7s = a7s * r1 * r2;                                              \
        ls_e += E_prev - 100;                                             \
        float m = fmaxf(fmaxf(fmaxf(A[0],A[1]), fmaxf(A[2],A[3])),        \
                        fmaxf(fmaxf(A[4],A[5]), fmaxf(A[6],A[7])));       \
        m = dpp_maxshr<0x111>(m);   /* row_shr:1 */                       \
        m = dpp_maxshr<0x112>(m);   /* row_shr:2 */                       \
        m = dpp_maxshr<0x114>(m);   /* row_shr:4 */                       \
        m = dpp_maxshr<0x118>(m);   /* row_shr:8 -> lane15 = max(l0..15) */ \
        int mi = __builtin_amdgcn_readlane(__float_as_int(m), 15);        \
        E_prev = ((mi >> 23) & 0xff) - 127;                               \
    }

    #define CAPTURE(CUR, gg)                                              \
    {                                                                     \
        _Pragma("unroll") for (int r = 0; r < 8; ++r) {                   \
            STEP(CUR[r]);                                                 \
            int k = (gg) * 8 + r + 1;                                     \
            if (k == kstar) {                                             \
                int yc = ycap & 7;                                        \
                float f = (yc==0)?A[0]:(yc==1)?A[1]:(yc==2)?A[2]:         \
                          (yc==3)?A[3]:(yc==4)?A[4]:(yc==5)?A[5]:         \
                          (yc==6)?A[6]:A[7];                              \
                fin = (l == (ycap >> 3)) ? f : 0.f;                       \
                fls = ls_e;                                               \
            }                                                             \
        }                                                                 \
    }

    int gg = 0;
    while (true) {
        if (gg == gstar) { CAPTURE(W0, gg); break; }
        LEAN(W0, W2, gg); gg++;                       // load grp gg+2
        if (gg == gstar) { CAPTURE(W1, gg); break; }
        LEAN(W1, W0, gg); gg++;
        if (gg == gstar) { CAPTURE(W2, gg); break; }
        LEAN(W2, W1, gg); gg++;
    }
    #undef STEP
    #undef LEAN
    #undef CAPTURE

    float fv = __shfl(fin, ycap >> 3);
    int   fe = __shfl(fls, ycap >> 3);
    if (l == 0) {
        float wbf = D[((size_t)kstar * RW + ycap) * 2];   // e^{blank[fcap,ycap]}
        out[b] = -(__logf(fv) + (float)fe * 0.69314718056f + __logf(wbf));
    }
}

extern "C" void kernel_launch(void* const* d_in, const int* in_sizes, int n_in,
                              void* d_out, int out_size, void* d_ws, size_t ws_size,
                              hipStream_t stream) {
    const float* x      = (const float*)d_in[0];
    const int*   label  = (const int*)d_in[1];
    const int*   f_len  = (const int*)d_in[2];
    const int*   y_len  = (const int*)d_in[3];
    const int*   blankp = (const int*)d_in[4];
    const float* lamp   = (const float*)d_in[5];
    float* out = (float*)d_out;

    float* D = (float*)d_ws;                          // B*ROWS*RW*2 floats

    (void)hipMemsetAsync(D, 0, (size_t)B * ROWS * RW * 2 * sizeof(float), stream);
    // MEASUREMENT: k_lse twice (idempotent). dur = C + 2*k_lse + k_alpha.
    k_lse<<<4096, 256, 0, stream>>>(x, label, f_len, y_len, blankp, lamp, D);
    k_lse<<<4096, 256, 0, stream>>>(x, label, f_len, y_len, blankp, lamp, D);
    k_alpha<<<B, 64, 0, stream>>>(D, f_len, y_len, out);
}

// Round 20
// 86.036 us; speedup vs baseline: 1.0613x; 1.0613x over previous
//
#include <hip/hip_runtime.h>

// RNN-T (transducer) loss, B=8 T=256 U=96 H=512, f32.
// Linear-domain wavefront DP: A[t,u] = A[t-1,u]*Wb[t-1,u] + A[t,u-1]*We[t,u-1]
// Wb=exp(blank_lp), We=exp(emit_lp) precomputed by k_lse into diagonal layout:
// Wb(t,u) -> row t+u, col u, slot0;  We(t,u) -> row t+u, col u+1, slot1.
// hipMemsetAsync zeroes the ENTIRE D buffer (zero weight self-masks all
// dead/unwritten cells). k_alpha: DPP cross-lane + triple-buffered prefetch.
// NOTE (measurement round 2): k_alpha is launched TWICE (idempotent) so
// dur = C + k_lse + 2*k_alpha; combined with R19 (C + 2*k_lse + k_alpha =
// 91.3) this pins both kernel durations.
constexpr int B = 8, T = 256, U = 96, H = 512;
constexpr int RW = 96, ROWS = 368;   // float2 {wb,we} per cell
constexpr int CH = 12;               // rows per k_lse chunk (straggler bound)

typedef float vf4 __attribute__((ext_vector_type(4)));

__device__ __forceinline__ float exp2i(int e) {      // e in [-126,127]
    return __uint_as_float((unsigned)(127 + e) << 23);
}

// lane l <- x[lane l-1]; lane 0 <- 0.  Pure-VALU shfl_up(x,1): DPP wave_shr:1.
__device__ __forceinline__ float dpp_up1(float x) {
    return __int_as_float(__builtin_amdgcn_update_dpp(
        0, __float_as_int(x), 0x138, 0xf, 0xf, true));
}
// fmax with row_shr:N shifted self (accumulates max toward higher lanes).
template <int CTRL>
__device__ __forceinline__ float dpp_maxshr(float x) {
    return fmaxf(x, __int_as_float(__builtin_amdgcn_update_dpp(
        0, __float_as_int(x), CTRL, 0xf, 0xf, true)));
}

// Kernel 1 (R19-identical): one wave per 12-row chunk; 4 rows per iteration
// via 16-lane quarters (4-level reduce), plain loads, launch_bounds(256,8).
__global__ __launch_bounds__(256, 8) void k_lse(
    const float* __restrict__ x, const int* __restrict__ label,
    const int* __restrict__ f_len, const int* __restrict__ y_len,
    const int* __restrict__ blank_p, const float* __restrict__ lam_p,
    float* __restrict__ D)
{
    const int tid  = threadIdx.x;
    const int lane = tid & 63;
    const int l16  = lane & 15;
    const int q    = lane >> 4;               // quarter id = row offset
    const int chunk = (blockIdx.x << 2) | (tid >> 6);   // 0..16383
    const int b  = chunk & 7;                 // b fastest: balanced dead work
    const int t  = (chunk >> 3) & 255;
    const int u0 = (chunk >> 11) * CH;        // 0,12,...,84

    const int fb = f_len[b], yb = y_len[b];
    if (t >= fb || u0 > yb) return;                    // dead chunk
    const int nbl = min(CH, yb + 1 - u0);              // rows with Wb write
    const int nem = min(CH, yb - u0);                  // rows with We write

    const int ib   = blank_p[0];
    const float lam = lam_p[0];
    const float pen = lam * ((fb - 1.0f) * 0.5f) - lam * (float)t;

    int lbl_l = 0;                                     // labels u0..u0+11
    if (lane < CH && (u0 + lane) < U - 1)
        lbl_l = label[b * (U - 1) + u0 + lane];

    const float* xrow = x + ((size_t)(b * T + t) * U + u0) * H;
    size_t cc0 = ((size_t)b * ROWS + (t + u0)) * RW + u0;

    for (int i = 0; i < nbl; i += 4) {
        const int row = i + q;                 // quarter q handles row i+q
        const bool rv = row < nbl;
        const float* xr = xrow + (size_t)row * H;

        // scalar pre-load for the two storer lanes (latency hidden below)
        int  lbl = __shfl(lbl_l, row & 15);
        int  idx = (l16 == 0) ? ib : lbl;
        float xs = 0.f;
        if (rv && l16 < 2) xs = xr[idx];

        vf4 v[8];
        #pragma unroll
        for (int j = 0; j < 8; ++j) {
            vf4 z = {0.f, 0.f, 0.f, 0.f};
            v[j] = rv ? ((const vf4*)xr)[l16 + 16 * j] : z;
        }
        float s0 = 0.f, s1 = 0.f, s2 = 0.f, s3 = 0.f;
        #pragma unroll
        for (int j = 0; j < 8; ++j) {
            s0 += __expf(v[j].x); s1 += __expf(v[j].y);
            s2 += __expf(v[j].z); s3 += __expf(v[j].w);
        }
        float s = (s0 + s1) + (s2 + s3);
        #pragma unroll
        for (int d = 1; d < 16; d <<= 1) s += __shfl_xor(s, d);
        float rcp = __builtin_amdgcn_rcpf(s);          // W = exp(x)/s

        size_t cc = cc0 + (size_t)row * (RW + 1);
        if (rv && l16 == 0) D[cc * 2] = __expf(xs) * rcp;            // Wb
        if (rv && row < nem && l16 == 1)
            D[(cc + 1) * 2 + 1] = __expf(xs + pen) * rcp;            // We
    }
}

// Kernel 2 (R18/R19-identical): wavefront DP. One wave per batch. Lane l
// (0..11) owns u-strip [8l, 8l+7]. 16 FMA + 1 DPP per step; triple-buffered
// group prefetch; stale-by-one-group power-of-2 rescale, bias 2^100.
__global__ __launch_bounds__(64) void k_alpha(
    const float* __restrict__ D_all,
    const int* __restrict__ f_len, const int* __restrict__ y_len,
    float* __restrict__ out)
{
    const int b = blockIdx.x;
    const int l = threadIdx.x;
    const float* D = D_all + (size_t)b * ROWS * RW * 2;
    const vf4* Dv = (const vf4*)D;                    // 48 vf4 per diag row
    const int lc = (l < 12) ? l : 11;
    const int fcap = f_len[b] - 1;
    const int ycap = y_len[b];
    const int kstar = fcap + ycap;                    // in [135, 350]
    const int gstar = (kstar - 1) >> 3;               // group holding kstar (>=16)

    float A[8];
    #pragma unroll
    for (int c = 0; c < 8; ++c) A[c] = 0.f;
    if (l == 0) A[0] = 1.f;                           // alpha[0,0] = 1
    float a7s = 0.f;                                  // col 8l-1 prev-diag value
    int ls_e = 0, E_prev = 0, fls = 0;
    float fin = 0.f;

    vf4 W0[8][4], W1[8][4], W2[8][4];
    #pragma unroll
    for (int r = 0; r < 8; ++r)
        #pragma unroll
        for (int qq = 0; qq < 4; ++qq) {
            W0[r][qq] = Dv[(size_t)r * (RW / 2) + lc * 4 + qq];        // grp 0
            W1[r][qq] = Dv[(size_t)(8 + r) * (RW / 2) + lc * 4 + qq];  // grp 1
        }

    #define STEP(WROW)                                                    \
    {                                                                     \
        float n7 = fmaf(A[6], (WROW)[3].w, A[7] * (WROW)[3].z);           \
        float n0 = fmaf(a7s,  (WROW)[0].y, A[0] * (WROW)[0].x);           \
        float n1 = fmaf(A[0], (WROW)[0].w, A[1] * (WROW)[0].z);           \
        float n2 = fmaf(A[1], (WROW)[1].y, A[2] * (WROW)[1].x);           \
        float n3 = fmaf(A[2], (WROW)[1].w, A[3] * (WROW)[1].z);           \
        float n4 = fmaf(A[3], (WROW)[2].y, A[4] * (WROW)[2].x);           \
        float n5 = fmaf(A[4], (WROW)[2].w, A[5] * (WROW)[2].z);           \
        float n6 = fmaf(A[5], (WROW)[3].y, A[6] * (WROW)[3].x);           \
        a7s = dpp_up1(n7);                                                \
        A[0]=n0; A[1]=n1; A[2]=n2; A[3]=n3;                               \
        A[4]=n4; A[5]=n5; A[6]=n6; A[7]=n7;                               \
    }

    // Step group gg from CUR; load group gg+2 into NXT; stale rescale.
    #define LEAN(CUR, NXT, gg)                                            \
    {                                                                     \
        _Pragma("unroll") for (int r = 0; r < 8; ++r)                     \
            _Pragma("unroll") for (int qq = 0; qq < 4; ++qq)              \
                NXT[r][qq] = Dv[((size_t)((gg)+2)*8 + r)*(RW/2) + lc*4 + qq]; \
        _Pragma("unroll") for (int r = 0; r < 8; ++r) STEP(CUR[r]);       \
        int sh = 100 - E_prev;                                            \
        float r1 = exp2i(sh >> 1), r2 = exp2i(sh - (sh >> 1));            \
        _Pragma("unroll") for (int c = 0; c < 8; ++c) A[c] = A[c]*r1*r2;  \
        a7s = a7s * r1 * r2;                                              \
        ls_e += E_prev - 100;                                             \
        float m = fmaxf(fmaxf(fmaxf(A[0],A[1]), fmaxf(A[2],A[3])),        \
                        fmaxf(fmaxf(A[4],A[5]), fmaxf(A[6],A[7])));       \
        m = dpp_maxshr<0x111>(m);   /* row_shr:1 */                       \
        m = dpp_maxshr<0x112>(m);   /* row_shr:2 */                       \
        m = dpp_maxshr<0x114>(m);   /* row_shr:4 */                       \
        m = dpp_maxshr<0x118>(m);   /* row_shr:8 -> lane15 = max(l0..15) */ \
        int mi = __builtin_amdgcn_readlane(__float_as_int(m), 15);        \
        E_prev = ((mi >> 23) & 0xff) - 127;                               \
    }

    #define CAPTURE(CUR, gg)                                              \
    {                                                                     \
        _Pragma("unroll") for (int r = 0; r < 8; ++r) {                   \
            STEP(CUR[r]);                                                 \
            int k = (gg) * 8 + r + 1;                                     \
            if (k == kstar) {                                             \
                int yc = ycap & 7;                                        \
                float f = (yc==0)?A[0]:(yc==1)?A[1]:(yc==2)?A[2]:         \
                          (yc==3)?A[3]:(yc==4)?A[4]:(yc==5)?A[5]:         \
                          (yc==6)?A[6]:A[7];                              \
                fin = (l == (ycap >> 3)) ? f : 0.f;                       \
                fls = ls_e;                                               \
            }                                                             \
        }                                                                 \
    }

    int gg = 0;
    while (true) {
        if (gg == gstar) { CAPTURE(W0, gg); break; }
        LEAN(W0, W2, gg); gg++;                       // load grp gg+2
        if (gg == gstar) { CAPTURE(W1, gg); break; }
        LEAN(W1, W0, gg); gg++;
        if (gg == gstar) { CAPTURE(W2, gg); break; }
        LEAN(W2, W1, gg); gg++;
    }
    #undef STEP
    #undef LEAN
    #undef CAPTURE

    float fv = __shfl(fin, ycap >> 3);
    int   fe = __shfl(fls, ycap >> 3);
    if (l == 0) {
        float wbf = D[((size_t)kstar * RW + ycap) * 2];   // e^{blank[fcap,ycap]}
        out[b] = -(__logf(fv) + (float)fe * 0.69314718056f + __logf(wbf));
    }
}

extern "C" void kernel_launch(void* const* d_in, const int* in_sizes, int n_in,
                              void* d_out, int out_size, void* d_ws, size_t ws_size,
                              hipStream_t stream) {
    const float* x      = (const float*)d_in[0];
    const int*   label  = (const int*)d_in[1];
    const int*   f_len  = (const int*)d_in[2];
    const int*   y_len  = (const int*)d_in[3];
    const int*   blankp = (const int*)d_in[4];
    const float* lamp   = (const float*)d_in[5];
    float* out = (float*)d_out;

    float* D = (float*)d_ws;                          // B*ROWS*RW*2 floats

    (void)hipMemsetAsync(D, 0, (size_t)B * ROWS * RW * 2 * sizeof(float), stream);
    k_lse<<<4096, 256, 0, stream>>>(x, label, f_len, y_len, blankp, lamp, D);
    // MEASUREMENT: k_alpha twice (idempotent). dur = C + k_lse + 2*k_alpha.
    k_alpha<<<B, 64, 0, stream>>>(D, f_len, y_len, out);
    k_alpha<<<B, 64, 0, stream>>>(D, f_len, y_len, out);
}

// Round 22
// 42.931 us; speedup vs baseline: 2.1268x; 2.0040x over previous
//
#include <hip/hip_runtime.h>

// RNN-T (transducer) loss, B=8 T=256 U=96 H=512, f32.
// Linear-domain wavefront DP: A[t,u] = A[t-1,u]*Wb[t-1,u] + A[t,u-1]*We[t,u-1]
// Wb=exp(blank_lp), We=exp(emit_lp) precomputed by k_lse into diagonal layout:
// Wb(t,u) -> row t+u, col u, slot0;  We(t,u) -> row t+u, col u+1, slot1.
// NO memset: the valid region's read-set equals k_lse's write-set exactly;
// garbage (poison) cells only feed garbage cells (rightward/downward flow),
// decay multiplicatively, are masked out of the rescale max, and the
// power-of-2 rescale is exactly compensated by ls_e regardless of its value.
constexpr int B = 8, T = 256, U = 96, H = 512;
constexpr int RW = 96, ROWS = 384;   // float2 {wb,we} per cell
constexpr int CH = 12;               // rows per k_lse chunk (straggler bound)

typedef float vf4 __attribute__((ext_vector_type(4)));

__device__ __forceinline__ float exp2i(int e) {      // e in [-126,127]
    return __uint_as_float((unsigned)(127 + e) << 23);
}

// lane l <- x[lane l-1]; lane 0 <- 0.  Pure-VALU shfl_up(x,1): DPP wave_shr:1.
__device__ __forceinline__ float dpp_up1(float x) {
    return __int_as_float(__builtin_amdgcn_update_dpp(
        0, __float_as_int(x), 0x138, 0xf, 0xf, true));
}
// fmax with DPP-shifted self (accumulates max toward higher lanes).
template <int CTRL>
__device__ __forceinline__ float dpp_maxshr(float x) {
    return fmaxf(x, __int_as_float(__builtin_amdgcn_update_dpp(
        0, __float_as_int(x), CTRL, 0xf, 0xf, true)));
}

// Kernel 1 (R19-identical, ROWS=384): one wave per 12-row chunk; 4 rows per
// iteration via 16-lane quarters (4-level reduce), plain loads.
__global__ __launch_bounds__(256, 8) void k_lse(
    const float* __restrict__ x, const int* __restrict__ label,
    const int* __restrict__ f_len, const int* __restrict__ y_len,
    const int* __restrict__ blank_p, const float* __restrict__ lam_p,
    float* __restrict__ D)
{
    const int tid  = threadIdx.x;
    const int lane = tid & 63;
    const int l16  = lane & 15;
    const int q    = lane >> 4;               // quarter id = row offset
    const int chunk = (blockIdx.x << 2) | (tid >> 6);   // 0..16383
    const int b  = chunk & 7;                 // b fastest: balanced dead work
    const int t  = (chunk >> 3) & 255;
    const int u0 = (chunk >> 11) * CH;        // 0,12,...,84

    const int fb = f_len[b], yb = y_len[b];
    if (t >= fb || u0 > yb) return;                    // dead chunk
    const int nbl = min(CH, yb + 1 - u0);              // rows with Wb write
    const int nem = min(CH, yb - u0);                  // rows with We write

    const int ib   = blank_p[0];
    const float lam = lam_p[0];
    const float pen = lam * ((fb - 1.0f) * 0.5f) - lam * (float)t;

    int lbl_l = 0;                                     // labels u0..u0+11
    if (lane < CH && (u0 + lane) < U - 1)
        lbl_l = label[b * (U - 1) + u0 + lane];

    const float* xrow = x + ((size_t)(b * T + t) * U + u0) * H;
    size_t cc0 = ((size_t)b * ROWS + (t + u0)) * RW + u0;

    for (int i = 0; i < nbl; i += 4) {
        const int row = i + q;                 // quarter q handles row i+q
        const bool rv = row < nbl;
        const float* xr = xrow + (size_t)row * H;

        // scalar pre-load for the two storer lanes (latency hidden below)
        int  lbl = __shfl(lbl_l, row & 15);
        int  idx = (l16 == 0) ? ib : lbl;
        float xs = 0.f;
        if (rv && l16 < 2) xs = xr[idx];

        vf4 v[8];
        #pragma unroll
        for (int j = 0; j < 8; ++j) {
            vf4 z = {0.f, 0.f, 0.f, 0.f};
            v[j] = rv ? ((const vf4*)xr)[l16 + 16 * j] : z;
        }
        float s0 = 0.f, s1 = 0.f, s2 = 0.f, s3 = 0.f;
        #pragma unroll
        for (int j = 0; j < 8; ++j) {
            s0 += __expf(v[j].x); s1 += __expf(v[j].y);
            s2 += __expf(v[j].z); s3 += __expf(v[j].w);
        }
        float s = (s0 + s1) + (s2 + s3);
        #pragma unroll
        for (int d = 1; d < 16; d <<= 1) s += __shfl_xor(s, d);
        float rcp = __builtin_amdgcn_rcpf(s);          // W = exp(x)/s

        size_t cc = cc0 + (size_t)row * (RW + 1);
        if (rv && l16 == 0) D[cc * 2] = __expf(xs) * rcp;            // Wb
        if (rv && row < nem && l16 == 1)
            D[(cc + 1) * 2 + 1] = __expf(xs + pen) * rcp;            // We
    }
}

// Kernel 2: wavefront DP, 48-lane layout. Lane l (0..47) owns cols 2l, 2l+1
// -> ONE vf4 per lane per diag row (768B coalesced row load), buffer = 8
// VGPRs/group -> 5 buffers, prefetch 4 groups ahead (~600+cyc latency cover).
// Per step: 2 FMA + 1 DPP wave_shr:1. Wave-wide max via DPP shr/bcast tree.
// Stale-by-one-group power-of-2 rescale, bias 2^100 (exactly ls_e-compensated).
__global__ __launch_bounds__(64) void k_alpha(
    const float* __restrict__ D_all,
    const int* __restrict__ f_len, const int* __restrict__ y_len,
    float* __restrict__ out)
{
    const int b = blockIdx.x;
    const int l = threadIdx.x;
    const float* D = D_all + (size_t)b * ROWS * RW * 2;
    const vf4* Dv = (const vf4*)D;                    // 48 vf4 per diag row
    const int fcap = f_len[b] - 1;
    const int ycap = y_len[b];
    const int kstar = fcap + ycap;                    // in [135, 350]
    const int gstar = (kstar - 1) >> 3;               // group holding kstar (>=16)

    float A0 = (l == 0) ? 1.f : 0.f;                  // alpha[0,0] = 1
    float A1 = 0.f;
    float a1s = 0.f;                                  // col 2l-1 prev-diag value
    int ls_e = 0, E_prev = 0, fls = 0;
    float fin = 0.f;

    vf4 W0[8], W1[8], W2[8], W3[8], W4[8];
    #pragma unroll
    for (int r = 0; r < 8; ++r) {                     // groups 0..3 prologue
        W0[r] = Dv[(size_t)(0 * 8 + r) * (RW / 2) + l];
        W1[r] = Dv[(size_t)(1 * 8 + r) * (RW / 2) + l];
        W2[r] = Dv[(size_t)(2 * 8 + r) * (RW / 2) + l];
        W3[r] = Dv[(size_t)(3 * 8 + r) * (RW / 2) + l];
    }

    #define STEP(wt)                                                      \
    {                                                                     \
        float n0 = fmaf(a1s, (wt).y, A0 * (wt).x);                        \
        float n1 = fmaf(A0,  (wt).w, A1 * (wt).z);                        \
        a1s = dpp_up1(n1);                                                \
        A0 = n0; A1 = n1;                                                 \
    }

    // Step group gg from CUR; load group gg+4 into NXT; stale rescale.
    #define LEAN(CUR, NXT, gg)                                            \
    {                                                                     \
        _Pragma("unroll") for (int r = 0; r < 8; ++r)                     \
            NXT[r] = Dv[((size_t)((gg) + 4) * 8 + r) * (RW / 2) + l];     \
        _Pragma("unroll") for (int r = 0; r < 8; ++r) STEP(CUR[r]);       \
        int sh = 100 - E_prev;                                            \
        float r1 = exp2i(sh >> 1), r2 = exp2i(sh - (sh >> 1));            \
        A0 = A0 * r1 * r2; A1 = A1 * r1 * r2; a1s = a1s * r1 * r2;        \
        ls_e += E_prev - 100;                                             \
        float m = fmaxf(A0, A1);                                          \
        m = (l < 48) ? m : 0.f;                                           \
        m = dpp_maxshr<0x111>(m);   /* row_shr:1  */                      \
        m = dpp_maxshr<0x112>(m);   /* row_shr:2  */                      \
        m = dpp_maxshr<0x114>(m);   /* row_shr:4  */                      \
        m = dpp_maxshr<0x118>(m);   /* row_shr:8  */                      \
        m = dpp_maxshr<0x142>(m);   /* row_bcast:15 */                    \
        m = dpp_maxshr<0x143>(m);   /* row_bcast:31 -> lane63 = wave max */ \
        int mi = __builtin_amdgcn_readlane(__float_as_int(m), 63);        \
        E_prev = ((mi >> 23) & 0xff) - 127;                               \
    }

    #define CAPTURE(CUR, gg)                                              \
    {                                                                     \
        _Pragma("unroll") for (int r = 0; r < 8; ++r) {                   \
            STEP(CUR[r]);                                                 \
            int k = (gg) * 8 + r + 1;                                     \
            if (k == kstar) {                                             \
                float f = (ycap & 1) ? A1 : A0;                           \
                fin = (l == (ycap >> 1)) ? f : 0.f;                       \
                fls = ls_e;                                               \
            }                                                             \
        }                                                                 \
    }

    int gg = 0;
    while (true) {
        if (gg == gstar) { CAPTURE(W0, gg); break; }
        LEAN(W0, W4, gg); gg++;
        if (gg == gstar) { CAPTURE(W1, gg); break; }
        LEAN(W1, W0, gg); gg++;
        if (gg == gstar) { CAPTURE(W2, gg); break; }
        LEAN(W2, W1, gg); gg++;
        if (gg == gstar) { CAPTURE(W3, gg); break; }
        LEAN(W3, W2, gg); gg++;
        if (gg == gstar) { CAPTURE(W4, gg); break; }
        LEAN(W4, W3, gg); gg++;
    }
    #undef STEP
    #undef LEAN
    #undef CAPTURE

    float fv = __shfl(fin, ycap >> 1);
    int   fe = __shfl(fls, ycap >> 1);
    if (l == 0) {
        float wbf = D[((size_t)kstar * RW + ycap) * 2];   // e^{blank[fcap,ycap]}
        out[b] = -(__logf(fv) + (float)fe * 0.69314718056f + __logf(wbf));
    }
}

extern "C" void kernel_launch(void* const* d_in, const int* in_sizes, int n_in,
                              void* d_out, int out_size, void* d_ws, size_t ws_size,
                              hipStream_t stream) {
    const float* x      = (const float*)d_in[0];
    const int*   label  = (const int*)d_in[1];
    const int*   f_len  = (const int*)d_in[2];
    const int*   y_len  = (const int*)d_in[3];
    const int*   blankp = (const int*)d_in[4];
    const float* lamp   = (const float*)d_in[5];
    float* out = (float*)d_out;

    float* D = (float*)d_ws;                          // B*ROWS*RW*2 floats

    k_lse<<<4096, 256, 0, stream>>>(x, label, f_len, y_len, blankp, lamp, D);
    k_alpha<<<B, 64, 0, stream>>>(D, f_len, y_len, out);
}